// Round 1
// baseline (96.133 us; speedup 1.0000x reference)
//
#include <hip/hip_runtime.h>

#define BATCH 999
#define HID 1024
#define SEQ 160

#define BB 32                         // batches per block (4 waves x 8)
#define NBB ((BATCH + BB - 1) / BB)   // 32 b-blocks
#define HS 16                         // h-split (grid.x)
#define HPER (HID / HS)               // 64 h per block
#define HT 8                          // h rows staged per iteration
#define NT (HPER / HT)                // 8 iterations

#define AS1 __attribute__((address_space(1)))
#define AS3 __attribute__((address_space(3)))

// last-arrival counters, zero-initialized at module load, self-resetting
__device__ unsigned bcnt[NBB];

__global__ __launch_bounds__(256, 2)
void dots_kernel(const float* __restrict__ Cg, const float* __restrict__ Rg,
                 const float* __restrict__ Mg, float* __restrict__ ws,
                 float* __restrict__ out)
{
    __shared__ float sM[2][HT][HID];   // 64 KB, double-buffered M slab
    __shared__ float sC[HPER][BB];     // 8 KB, C transposed: sC[h][b]
    __shared__ int sdone;

    const int tid  = threadIdx.x;
    const int lane = tid & 63;
    const int w    = tid >> 6;        // wave id 0..3 -> owns 8 batches
    const int bx   = blockIdx.x;      // h-block 0..15
    const int by   = blockIdx.y;      // b-block 0..31
    const int h0   = bx * HPER;
    const int b0   = by * BB;

    // ---- stage C slice once: sC[h][b] = C[b0+b][last, h0+h] ----
    {
        const int b  = tid & 31;
        const int hq = tid >> 5;      // 0..7, 8 h-values each
        const int gb = b0 + b;
        float4 v0 = make_float4(0.f, 0.f, 0.f, 0.f), v1 = v0;
        if (gb < BATCH) {
            const float* cp = Cg + ((size_t)gb * SEQ + (SEQ - 1)) * HID + h0 + hq * 8;
            v0 = *(const float4*)cp;
            v1 = *(const float4*)(cp + 4);
        }
        // scattered b32 writes: bank = b -> 2-way wave64 aliasing = free
        sC[hq * 8 + 0][b] = v0.x; sC[hq * 8 + 1][b] = v0.y;
        sC[hq * 8 + 2][b] = v0.z; sC[hq * 8 + 3][b] = v0.w;
        sC[hq * 8 + 4][b] = v1.x; sC[hq * 8 + 5][b] = v1.y;
        sC[hq * 8 + 6][b] = v1.z; sC[hq * 8 + 7][b] = v1.w;
    }

    // ---- prologue: async-stage M rows h0..h0+7 into buf 0 ----
    {
        const float* g0 = Mg + (size_t)h0 * HID + w * 256 + (lane << 2);
        #pragma unroll
        for (int i = 0; i < HT; ++i) {
            __builtin_amdgcn_global_load_lds(
                (const AS1 void*)(g0 + (size_t)i * HID),
                (AS3 void*)(&sM[0][i][w * 256]), 16, 0, 0);
        }
    }
    __syncthreads();   // drains prologue loads

    float4 acc[8][4];  // 8 batches x 16 k (k = lane*4 + j*256 + 0..3)
    #pragma unroll
    for (int i = 0; i < 8; ++i)
        #pragma unroll
        for (int j = 0; j < 4; ++j) acc[i][j] = make_float4(0.f, 0.f, 0.f, 0.f);

    for (int t = 0; t < NT; ++t) {
        const int buf = t & 1;
        // prefetch next M slab AFTER the barrier: its latency hides under FMAs
        if (t + 1 < NT) {
            const float* g0 = Mg + (size_t)(h0 + (t + 1) * HT) * HID + w * 256 + (lane << 2);
            #pragma unroll
            for (int i = 0; i < HT; ++i) {
                __builtin_amdgcn_global_load_lds(
                    (const AS1 void*)(g0 + (size_t)i * HID),
                    (AS3 void*)(&sM[buf ^ 1][i][w * 256]), 16, 0, 0);
            }
        }
        #pragma unroll
        for (int hh = 0; hh < HT; ++hh) {
            // 4 distinct ds_read_b128, lane stride 16B (measured-good pattern)
            const float* mrow = &sM[buf][hh][lane << 2];
            const float4 m0 = *(const float4*)(mrow);
            const float4 m1 = *(const float4*)(mrow + 256);
            const float4 m2 = *(const float4*)(mrow + 512);
            const float4 m3 = *(const float4*)(mrow + 768);
            // 2 wave-uniform broadcast ds_read_b128 (8 c-values for this wave)
            const float* crow = &sC[t * HT + hh][w * 8];
            const float4 ca = *(const float4*)crow;
            const float4 cb = *(const float4*)(crow + 4);
            const float cs[8] = {ca.x, ca.y, ca.z, ca.w, cb.x, cb.y, cb.z, cb.w};
            #pragma unroll
            for (int i = 0; i < 8; ++i) {
                acc[i][0].x += cs[i] * m0.x; acc[i][0].y += cs[i] * m0.y;
                acc[i][0].z += cs[i] * m0.z; acc[i][0].w += cs[i] * m0.w;
                acc[i][1].x += cs[i] * m1.x; acc[i][1].y += cs[i] * m1.y;
                acc[i][1].z += cs[i] * m1.z; acc[i][1].w += cs[i] * m1.w;
                acc[i][2].x += cs[i] * m2.x; acc[i][2].y += cs[i] * m2.y;
                acc[i][2].z += cs[i] * m2.z; acc[i][2].w += cs[i] * m2.w;
                acc[i][3].x += cs[i] * m3.x; acc[i][3].y += cs[i] * m3.y;
                acc[i][3].z += cs[i] * m3.z; acc[i][3].w += cs[i] * m3.w;
            }
        }
        __syncthreads();  // protects buf reuse + drains prefetch (latency covered)
    }

    // ---- epilogue: dot with R rows, 64-lane butterfly, atomic accumulate ----
    #pragma unroll
    for (int i = 0; i < 8; ++i) {
        const int gb = b0 + w * 8 + i;
        float p = 0.f;
        if (gb < BATCH) {
            const float* rp = Rg + ((size_t)gb * SEQ + (SEQ - 1)) * HID + (lane << 2);
            const float4 r0 = *(const float4*)(rp);
            const float4 r1 = *(const float4*)(rp + 256);
            const float4 r2 = *(const float4*)(rp + 512);
            const float4 r3 = *(const float4*)(rp + 768);
            p = acc[i][0].x * r0.x + acc[i][0].y * r0.y + acc[i][0].z * r0.z + acc[i][0].w * r0.w
              + acc[i][1].x * r1.x + acc[i][1].y * r1.y + acc[i][1].z * r1.z + acc[i][1].w * r1.w
              + acc[i][2].x * r2.x + acc[i][2].y * r2.y + acc[i][2].z * r2.z + acc[i][2].w * r2.w
              + acc[i][3].x * r3.x + acc[i][3].y * r3.y + acc[i][3].z * r3.z + acc[i][3].w * r3.w;
        }
        #pragma unroll
        for (int m = 1; m < 64; m <<= 1) p += __shfl_xor(p, m, 64);
        if (lane == 0 && gb < BATCH) atomicAdd(&ws[gb], p);
    }

    // ---- fused sigmoid: last h-block for this b-group finishes the batches ----
    __threadfence();          // release: make our ws atomics visible device-wide
    __syncthreads();
    if (tid == 0) {
        unsigned old = atomicAdd(&bcnt[by], 1u);
        sdone = (old == HS - 1) ? 1 : 0;
        if (old == HS - 1) atomicExch(&bcnt[by], 0u);   // self-reset for next launch
    }
    __syncthreads();
    if (sdone) {
        __threadfence();      // acquire side
        if (tid < BB) {
            const int gb = b0 + tid;
            if (gb < BATCH) {
                float d = atomicAdd(&ws[gb], 0.0f);   // coherent read of the sum
                out[gb] = 1.f / (1.f + __expf(-d));
            }
        }
    }
}

extern "C" void kernel_launch(void* const* d_in, const int* in_sizes, int n_in,
                              void* d_out, int out_size, void* d_ws, size_t ws_size,
                              hipStream_t stream) {
    const float* ctx = (const float*)d_in[0];
    const float* rsp = (const float*)d_in[1];
    const float* M   = (const float*)d_in[2];
    float* out = (float*)d_out;
    float* ws  = (float*)d_ws;

    hipMemsetAsync(ws, 0, BATCH * sizeof(float), stream);

    dim3 grid(HS, NBB);   // 16 h-blocks x 32 b-blocks = 512 blocks, 2/CU
    dots_kernel<<<grid, 256, 0, stream>>>(ctx, rsp, M, ws, out);
}

// Round 2
// 52.844 us; speedup vs baseline: 1.8192x; 1.8192x over previous
//
#include <hip/hip_runtime.h>

#define BATCH 999
#define HID 1024
#define SEQ 160

#define BB 32                         // batches per block (4 waves x 8)
#define NBB ((BATCH + BB - 1) / BB)   // 32 b-blocks
#define KS 2                          // k-split
#define KPER (HID / KS)               // 512 k per block
#define HS 16                         // h-split
#define HPER (HID / HS)               // 64 h per block
#define HT 4                          // h rows staged per iteration (= #waves)
#define NT (HPER / HT)                // 16 iterations

#define AS1 __attribute__((address_space(1)))
#define AS3 __attribute__((address_space(3)))

__global__ __launch_bounds__(256, 3)
void dots_kernel(const float* __restrict__ Cg, const float* __restrict__ Rg,
                 const float* __restrict__ Mg, float* __restrict__ ws)
{
    __shared__ float sM[2][HT][KPER];  // 16 KB double-buffered M slab
    __shared__ float sC[HPER][BB];     // 8 KB, C transposed: sC[h][b]

    const int tid  = threadIdx.x;
    const int lane = tid & 63;
    const int w    = tid >> 6;        // wave id 0..3 -> owns 8 batches, stages row w
    const int by   = blockIdx.x;      // b-block 0..31  (XCD = by%8: C/R locality)
    const int kx   = blockIdx.y & 1;  // k-half
    const int hz   = blockIdx.y >> 1; // h-slice 0..15
    const int b0   = by * BB;
    const int k0   = kx * KPER;
    const int h0   = hz * HPER;

    // ---- stage C slice once: sC[h][b] = C[b0+b][last, h0+h] ----
    {
        const int b  = tid & 31;
        const int hq = tid >> 5;      // 0..7, 8 h-values each
        const int gb = b0 + b;
        float4 v0 = make_float4(0.f, 0.f, 0.f, 0.f), v1 = v0;
        if (gb < BATCH) {
            const float* cp = Cg + ((size_t)gb * SEQ + (SEQ - 1)) * HID + h0 + hq * 8;
            v0 = *(const float4*)cp;
            v1 = *(const float4*)(cp + 4);
        }
        // bank = b -> 2-way wave64 aliasing = free (m136)
        sC[hq * 8 + 0][b] = v0.x; sC[hq * 8 + 1][b] = v0.y;
        sC[hq * 8 + 2][b] = v0.z; sC[hq * 8 + 3][b] = v0.w;
        sC[hq * 8 + 4][b] = v1.x; sC[hq * 8 + 5][b] = v1.y;
        sC[hq * 8 + 6][b] = v1.z; sC[hq * 8 + 7][b] = v1.w;
    }

    // ---- prologue: async-stage M rows h0..h0+3 into buf 0 (wave w -> row w) ----
    {
        const float* g0 = Mg + (size_t)(h0 + w) * HID + k0 + (lane << 2);
        __builtin_amdgcn_global_load_lds((const AS1 void*)(g0),
                                         (AS3 void*)(&sM[0][w][lane << 2]), 16, 0, 0);
        __builtin_amdgcn_global_load_lds((const AS1 void*)(g0 + 256),
                                         (AS3 void*)(&sM[0][w][256 + (lane << 2)]), 16, 0, 0);
    }
    __syncthreads();   // drains prologue loads + sC writes

    float4 acc[8][2];  // 8 batches x 8 k-floats (k = k0 + lane*4 + j*256 + 0..3)
    #pragma unroll
    for (int i = 0; i < 8; ++i) {
        acc[i][0] = make_float4(0.f, 0.f, 0.f, 0.f);
        acc[i][1] = make_float4(0.f, 0.f, 0.f, 0.f);
    }

    for (int t = 0; t < NT; ++t) {
        const int cur = t & 1;
        // prefetch next slab into the other buffer; latency hides under FMAs
        if (t + 1 < NT) {
            const float* g0 = Mg + (size_t)(h0 + (t + 1) * HT + w) * HID + k0 + (lane << 2);
            __builtin_amdgcn_global_load_lds((const AS1 void*)(g0),
                                             (AS3 void*)(&sM[cur ^ 1][w][lane << 2]), 16, 0, 0);
            __builtin_amdgcn_global_load_lds((const AS1 void*)(g0 + 256),
                                             (AS3 void*)(&sM[cur ^ 1][w][256 + (lane << 2)]), 16, 0, 0);
        }
        #pragma unroll
        for (int hh = 0; hh < HT; ++hh) {
            // 2 ds_read_b128, lane stride 16B (measured-good pattern)
            const float* mrow = &sM[cur][hh][lane << 2];
            const float4 m0 = *(const float4*)(mrow);
            const float4 m1 = *(const float4*)(mrow + 256);
            // 2 wave-uniform broadcast ds_read_b128 (this wave's 8 c-values)
            const float* crow = &sC[t * HT + hh][w * 8];
            const float4 ca = *(const float4*)crow;
            const float4 cb = *(const float4*)(crow + 4);
            const float cs[8] = {ca.x, ca.y, ca.z, ca.w, cb.x, cb.y, cb.z, cb.w};
            #pragma unroll
            for (int i = 0; i < 8; ++i) {
                acc[i][0].x += cs[i] * m0.x; acc[i][0].y += cs[i] * m0.y;
                acc[i][0].z += cs[i] * m0.z; acc[i][0].w += cs[i] * m0.w;
                acc[i][1].x += cs[i] * m1.x; acc[i][1].y += cs[i] * m1.y;
                acc[i][1].z += cs[i] * m1.z; acc[i][1].w += cs[i] * m1.w;
            }
        }
        __syncthreads();  // protects buf reuse + drains prefetch (covered by FMAs)
    }

    // ---- epilogue: dot with R rows, 64-lane butterfly, atomic accumulate ----
    #pragma unroll
    for (int i = 0; i < 8; ++i) {
        const int gb = b0 + w * 8 + i;
        float p = 0.f;
        if (gb < BATCH) {
            const float* rp = Rg + ((size_t)gb * SEQ + (SEQ - 1)) * HID + k0 + (lane << 2);
            const float4 r0 = *(const float4*)(rp);
            const float4 r1 = *(const float4*)(rp + 256);
            p = acc[i][0].x * r0.x + acc[i][0].y * r0.y + acc[i][0].z * r0.z + acc[i][0].w * r0.w
              + acc[i][1].x * r1.x + acc[i][1].y * r1.y + acc[i][1].z * r1.z + acc[i][1].w * r1.w;
        }
        #pragma unroll
        for (int m = 1; m < 64; m <<= 1) p += __shfl_xor(p, m, 64);
        if (lane == 0 && gb < BATCH) atomicAdd(&ws[gb], p);
    }
}

__global__ void sigmoid_kernel(const float* __restrict__ ws,
                               float* __restrict__ out, int n)
{
    int i = blockIdx.x * blockDim.x + threadIdx.x;
    if (i < n) {
        float d = ws[i];
        out[i] = 1.f / (1.f + __expf(-d));
    }
}

extern "C" void kernel_launch(void* const* d_in, const int* in_sizes, int n_in,
                              void* d_out, int out_size, void* d_ws, size_t ws_size,
                              hipStream_t stream) {
    const float* ctx = (const float*)d_in[0];
    const float* rsp = (const float*)d_in[1];
    const float* M   = (const float*)d_in[2];
    float* out = (float*)d_out;
    float* ws  = (float*)d_ws;

    hipMemsetAsync(ws, 0, BATCH * sizeof(float), stream);

    dim3 grid(NBB, KS * HS);   // 32 x 32 = 1024 blocks; XCD = by%8
    dots_kernel<<<grid, 256, 0, stream>>>(ctx, rsp, M, ws);

    sigmoid_kernel<<<(BATCH + 255) / 256, 256, 0, stream>>>(ws, out, BATCH);
}

// Round 3
// 51.520 us; speedup vs baseline: 1.8659x; 1.0257x over previous
//
#include <hip/hip_runtime.h>

#define BATCH 999
#define HID 1024
#define SEQ 160

#define BB 64                         // batches per block (4 waves x 16)
#define WB 16                         // batches per wave
#define NBB ((BATCH + BB - 1) / BB)   // 16 b-blocks
#define KS 2                          // k-split
#define KPER (HID / KS)               // 512 k per block
#define HS 16                         // h-split
#define HPER (HID / HS)               // 64 h per block

__global__ __launch_bounds__(256, 2)
void dots_kernel(const float* __restrict__ Cg, const float* __restrict__ Rg,
                 const float* __restrict__ Mg, float* __restrict__ ws)
{
    __shared__ float sC[HPER][BB];    // 16 KB, C transposed: sC[h][b]

    const int tid  = threadIdx.x;
    const int lane = tid & 63;
    const int w    = tid >> 6;        // wave id 0..3 -> owns 16 batches

    // XCD-aware decode: each XCD (= linear id % 8) gets 1 kx and 4 hz values
    // for ALL by -> per-XCD L2 working set: M 512KB + R-half 2MB + C 1MB < 4MB.
    const int L    = blockIdx.x;      // 0..511
    const int xcd  = L & 7;
    const int slot = L >> 3;          // 0..63
    const int tile = xcd * 4 + (slot & 3);   // 0..31
    const int by   = slot >> 2;       // 0..15
    const int kx   = tile >> 4;       // 0..1
    const int hz   = tile & 15;       // 0..15
    const int b0   = by * BB;
    const int k0   = kx * KPER;
    const int h0   = hz * HPER;

    // ---- stage C slice once: sC[h][b] = C[b0+b][last, h0+h] ----
    {
        const int b  = tid & 63;
        const int hq = tid >> 6;      // 0..3, 16 h-values each
        const int gb = b0 + b;
        float4 v[4];
        #pragma unroll
        for (int q = 0; q < 4; ++q) v[q] = make_float4(0.f, 0.f, 0.f, 0.f);
        if (gb < BATCH) {
            const float* cp = Cg + ((size_t)gb * SEQ + (SEQ - 1)) * HID + h0 + hq * 16;
            #pragma unroll
            for (int q = 0; q < 4; ++q) v[q] = *(const float4*)(cp + 4 * q);
        }
        // bank = b&31 -> 2-way wave64 aliasing = free
        #pragma unroll
        for (int q = 0; q < 4; ++q) {
            sC[hq * 16 + q * 4 + 0][b] = v[q].x;
            sC[hq * 16 + q * 4 + 1][b] = v[q].y;
            sC[hq * 16 + q * 4 + 2][b] = v[q].z;
            sC[hq * 16 + q * 4 + 3][b] = v[q].w;
        }
    }
    __syncthreads();   // the ONLY barrier

    float4 acc[WB][2]; // 16 batches x 8 k-floats (k = k0 + lane*4 + j*256*... )
    #pragma unroll
    for (int i = 0; i < WB; ++i) {
        acc[i][0] = make_float4(0.f, 0.f, 0.f, 0.f);
        acc[i][1] = make_float4(0.f, 0.f, 0.f, 0.f);
    }

    // M rows straight from global (L1/L2-resident, coalesced 16B/lane),
    // one-deep register prefetch, NO barriers, NO LDS for M.
    const float* mbase = Mg + (size_t)h0 * HID + k0 + (lane << 2);

    auto fmah = [&](int h, float4 ma, float4 mb) {
        const float* crow = &sC[h][w << 4];
        const float4 c0 = *(const float4*)(crow);       // wave-uniform broadcasts
        const float4 c1 = *(const float4*)(crow + 4);
        const float4 c2 = *(const float4*)(crow + 8);
        const float4 c3 = *(const float4*)(crow + 12);
        const float cs[WB] = {c0.x, c0.y, c0.z, c0.w, c1.x, c1.y, c1.z, c1.w,
                              c2.x, c2.y, c2.z, c2.w, c3.x, c3.y, c3.z, c3.w};
        #pragma unroll
        for (int i = 0; i < WB; ++i) {
            acc[i][0].x += cs[i] * ma.x; acc[i][0].y += cs[i] * ma.y;
            acc[i][0].z += cs[i] * ma.z; acc[i][0].w += cs[i] * ma.w;
            acc[i][1].x += cs[i] * mb.x; acc[i][1].y += cs[i] * mb.y;
            acc[i][1].z += cs[i] * mb.z; acc[i][1].w += cs[i] * mb.w;
        }
    };

    float4 m0a = *(const float4*)(mbase);
    float4 m0b = *(const float4*)(mbase + 256);
    float4 m1a = *(const float4*)(mbase + HID);
    float4 m1b = *(const float4*)(mbase + HID + 256);

    for (int h = 0; h < HPER - 2; h += 2) {
        const float* nb = mbase + (size_t)(h + 2) * HID;
        float4 n0a = *(const float4*)(nb);
        float4 n0b = *(const float4*)(nb + 256);
        float4 n1a = *(const float4*)(nb + HID);
        float4 n1b = *(const float4*)(nb + HID + 256);
        fmah(h, m0a, m0b);
        fmah(h + 1, m1a, m1b);
        m0a = n0a; m0b = n0b; m1a = n1a; m1b = n1b;
    }
    fmah(HPER - 2, m0a, m0b);
    fmah(HPER - 1, m1a, m1b);

    // ---- epilogue: dot with R rows, 64-lane butterfly, atomic accumulate ----
    #pragma unroll
    for (int i = 0; i < WB; ++i) {
        const int gb = b0 + w * WB + i;
        float p = 0.f;
        if (gb < BATCH) {
            const float* rp = Rg + ((size_t)gb * SEQ + (SEQ - 1)) * HID + k0 + (lane << 2);
            const float4 r0 = *(const float4*)(rp);
            const float4 r1 = *(const float4*)(rp + 256);
            p = acc[i][0].x * r0.x + acc[i][0].y * r0.y + acc[i][0].z * r0.z + acc[i][0].w * r0.w
              + acc[i][1].x * r1.x + acc[i][1].y * r1.y + acc[i][1].z * r1.z + acc[i][1].w * r1.w;
        }
        #pragma unroll
        for (int m = 1; m < 64; m <<= 1) p += __shfl_xor(p, m, 64);
        if (lane == 0 && gb < BATCH) atomicAdd(&ws[gb], p);
    }
}

__global__ void sigmoid_kernel(const float* __restrict__ ws,
                               float* __restrict__ out, int n)
{
    int i = blockIdx.x * blockDim.x + threadIdx.x;
    if (i < n) {
        float d = ws[i];
        out[i] = 1.f / (1.f + __expf(-d));
    }
}

extern "C" void kernel_launch(void* const* d_in, const int* in_sizes, int n_in,
                              void* d_out, int out_size, void* d_ws, size_t ws_size,
                              hipStream_t stream) {
    const float* ctx = (const float*)d_in[0];
    const float* rsp = (const float*)d_in[1];
    const float* M   = (const float*)d_in[2];
    float* out = (float*)d_out;
    float* ws  = (float*)d_ws;

    hipMemsetAsync(ws, 0, BATCH * sizeof(float), stream);

    dim3 grid(NBB * KS * HS);   // 512 blocks (1-D, XCD-aware decode), 2/CU
    dots_kernel<<<grid, 256, 0, stream>>>(ctx, rsp, M, ws);

    sigmoid_kernel<<<(BATCH + 255) / 256, 256, 0, stream>>>(ws, out, BATCH);
}

// Round 4
// 41.175 us; speedup vs baseline: 2.3347x; 1.2512x over previous
//
#include <hip/hip_runtime.h>

#define BATCH 999
#define HID 1024
#define SEQ 160

#define BB 64                         // batches per block (4 waves x 16)
#define WB 16                         // batches per wave
#define NBB 16                        // 16 * 64 = 1024 >= 999
#define KS 2                          // k-split
#define KPER (HID / KS)               // 512 k per block
#define HS 16                         // h-split
#define HPER (HID / HS)               // 64 h per block
#define NTILE (KS * HS)               // 32 hk-tiles per b-group

// Cross-block staging (device-coherent access only; zero-init not required:
// every slot is written each launch before it is read).
__device__ float gpart[NTILE][NBB][BB];     // 131 KB
__device__ unsigned gcnt[NBB];              // wraps mod 32 each launch: no reset

__global__ __launch_bounds__(256, 2)
void dots_kernel(const float* __restrict__ Cg, const float* __restrict__ Rg,
                 const float* __restrict__ Mg, float* __restrict__ out)
{
    __shared__ float sC[HPER][BB];    // 16 KB, C transposed: sC[h][b]
    __shared__ float sRed[4][BB];     // 1 KB, tail reduction
    __shared__ int sdone;

    const int tid  = threadIdx.x;
    const int lane = tid & 63;
    const int w    = tid >> 6;        // wave id 0..3 -> owns 16 batches

    // XCD-aware decode (bijective): per-XCD working set ~3.5 MB < 4 MB L2
    const int L    = blockIdx.x;      // 0..511
    const int xcd  = L & 7;
    const int slot = L >> 3;          // 0..63
    const int tile = xcd * 4 + (slot & 3);   // 0..31
    const int by   = slot >> 2;       // 0..15
    const int kx   = tile >> 4;       // 0..1
    const int hz   = tile & 15;       // 0..15
    const int b0   = by * BB;
    const int k0   = kx * KPER;
    const int h0   = hz * HPER;

    // ---- stage C slice once: sC[h][b] = C[b0+b][last, h0+h] ----
    {
        const int b  = tid & 63;
        const int hq = tid >> 6;      // 0..3, 16 h-values each
        const int gb = b0 + b;
        float4 v[4];
        #pragma unroll
        for (int q = 0; q < 4; ++q) v[q] = make_float4(0.f, 0.f, 0.f, 0.f);
        if (gb < BATCH) {
            const float* cp = Cg + ((size_t)gb * SEQ + (SEQ - 1)) * HID + h0 + hq * 16;
            #pragma unroll
            for (int q = 0; q < 4; ++q) v[q] = *(const float4*)(cp + 4 * q);
        }
        #pragma unroll
        for (int q = 0; q < 4; ++q) {
            sC[hq * 16 + q * 4 + 0][b] = v[q].x;
            sC[hq * 16 + q * 4 + 1][b] = v[q].y;
            sC[hq * 16 + q * 4 + 2][b] = v[q].z;
            sC[hq * 16 + q * 4 + 3][b] = v[q].w;
        }
    }
    __syncthreads();

    float4 acc[WB][2]; // 16 batches x 8 k-floats
    #pragma unroll
    for (int i = 0; i < WB; ++i) {
        acc[i][0] = make_float4(0.f, 0.f, 0.f, 0.f);
        acc[i][1] = make_float4(0.f, 0.f, 0.f, 0.f);
    }

    // M rows straight from global (L1/L2-resident, coalesced 16B/lane),
    // one-deep register prefetch, NO barriers, NO LDS for M.
    const float* mbase = Mg + (size_t)h0 * HID + k0 + (lane << 2);

    auto fmah = [&](int h, float4 ma, float4 mb) {
        const float* crow = &sC[h][w << 4];
        const float4 c0 = *(const float4*)(crow);       // wave-uniform broadcasts
        const float4 c1 = *(const float4*)(crow + 4);
        const float4 c2 = *(const float4*)(crow + 8);
        const float4 c3 = *(const float4*)(crow + 12);
        const float cs[WB] = {c0.x, c0.y, c0.z, c0.w, c1.x, c1.y, c1.z, c1.w,
                              c2.x, c2.y, c2.z, c2.w, c3.x, c3.y, c3.z, c3.w};
        #pragma unroll
        for (int i = 0; i < WB; ++i) {
            acc[i][0].x += cs[i] * ma.x; acc[i][0].y += cs[i] * ma.y;
            acc[i][0].z += cs[i] * ma.z; acc[i][0].w += cs[i] * ma.w;
            acc[i][1].x += cs[i] * mb.x; acc[i][1].y += cs[i] * mb.y;
            acc[i][1].z += cs[i] * mb.z; acc[i][1].w += cs[i] * mb.w;
        }
    };

    float4 m0a = *(const float4*)(mbase);
    float4 m0b = *(const float4*)(mbase + 256);
    float4 m1a = *(const float4*)(mbase + HID);
    float4 m1b = *(const float4*)(mbase + HID + 256);

    for (int h = 0; h < HPER - 2; h += 2) {
        const float* nb = mbase + (size_t)(h + 2) * HID;
        float4 n0a = *(const float4*)(nb);
        float4 n0b = *(const float4*)(nb + 256);
        float4 n1a = *(const float4*)(nb + HID);
        float4 n1b = *(const float4*)(nb + HID + 256);
        fmah(h, m0a, m0b);
        fmah(h + 1, m1a, m1b);
        m0a = n0a; m0b = n0b; m1a = n1a; m1b = n1b;
    }
    fmah(HPER - 2, m0a, m0b);
    fmah(HPER - 1, m1a, m1b);

    // ---- epilogue: dot with R rows, butterfly, coherent partial store ----
    #pragma unroll
    for (int i = 0; i < WB; ++i) {
        const int gb = b0 + w * WB + i;
        float p = 0.f;
        if (gb < BATCH) {
            const float* rp = Rg + ((size_t)gb * SEQ + (SEQ - 1)) * HID + k0 + (lane << 2);
            const float4 r0 = *(const float4*)(rp);
            const float4 r1 = *(const float4*)(rp + 256);
            p = acc[i][0].x * r0.x + acc[i][0].y * r0.y + acc[i][0].z * r0.z + acc[i][0].w * r0.w
              + acc[i][1].x * r1.x + acc[i][1].y * r1.y + acc[i][1].z * r1.z + acc[i][1].w * r1.w;
        }
        #pragma unroll
        for (int m = 1; m < 64; m <<= 1) p += __shfl_xor(p, m, 64);
        if (lane == 0)
            __hip_atomic_store(&gpart[tile][by][w * WB + i], p,
                               __ATOMIC_RELAXED, __HIP_MEMORY_SCOPE_AGENT);
    }

    // ---- completion protocol: waitcnt (stores at coherent point) -> counter ----
    asm volatile("s_waitcnt vmcnt(0)" ::: "memory");
    __syncthreads();
    if (tid == 0) {
        unsigned old = __hip_atomic_fetch_add(&gcnt[by], 1u,
                                              __ATOMIC_RELAXED, __HIP_MEMORY_SCOPE_AGENT);
        sdone = ((old & (NTILE - 1)) == (NTILE - 1));
    }
    __syncthreads();

    // ---- fused tail: last-arrival block reduces 32 partials + sigmoid ----
    if (sdone) {
        const int b = tid & 63;
        const int q = tid >> 6;       // 0..3 -> 8 tiles each
        float s = 0.f;
        #pragma unroll
        for (int t = 0; t < 8; ++t)
            s += __hip_atomic_load(&gpart[q * 8 + t][by][b],
                                   __ATOMIC_RELAXED, __HIP_MEMORY_SCOPE_AGENT);
        sRed[q][b] = s;
        __syncthreads();
        if (tid < BB) {
            const int gb = b0 + tid;
            if (gb < BATCH) {
                float d = sRed[0][tid] + sRed[1][tid] + sRed[2][tid] + sRed[3][tid];
                out[gb] = 1.f / (1.f + __expf(-d));
            }
        }
    }
}

extern "C" void kernel_launch(void* const* d_in, const int* in_sizes, int n_in,
                              void* d_out, int out_size, void* d_ws, size_t ws_size,
                              hipStream_t stream) {
    const float* ctx = (const float*)d_in[0];
    const float* rsp = (const float*)d_in[1];
    const float* M   = (const float*)d_in[2];
    float* out = (float*)d_out;
    (void)d_ws; (void)ws_size;

    dim3 grid(NBB * NTILE);   // 512 blocks, 1-D XCD-aware decode, 2/CU
    dots_kernel<<<grid, 256, 0, stream>>>(ctx, rsp, M, out);
}